// Round 6
// baseline (260.327 us; speedup 1.0000x reference)
//
#include <hip/hip_runtime.h>
#include <cstdint>

#define NH 6
#define HD 32
#define NTOK 256
#define CIN 576
#define DIMO 192
#define LOG2E 1.44269504f
#define SHIFT2 37.6f
#define MNEG (-144.269504f)   // -100 * log2(e)

typedef short short8 __attribute__((ext_vector_type(8)));
typedef float f32x4 __attribute__((ext_vector_type(4)));
typedef int   int4v __attribute__((ext_vector_type(4)));

__device__ __forceinline__ int grp6(int x) { return (x < 48) ? 0 : ((x < 56) ? 1 : 2); }

__device__ __forceinline__ unsigned short f2bf(float f) {
    unsigned int u = __float_as_uint(f);
    u += 0x7fffu + ((u >> 16) & 1u);   // RTNE
    return (unsigned short)(u >> 16);
}

// pack two f32 -> one dword of 2 bf16 (RTNE, bit-identical to f2bf pair)
__device__ __forceinline__ int pkbf(float lo, float hi) {
    int r;
    asm("v_cvt_pk_bf16_f32 %0, %1, %2" : "=v"(r) : "v"(lo), "v"(hi));
    return r;
}

// Tile-linear swizzled offset (in shorts) for the Q/K fragment buffers.
// byte = tile*1024 + row*64 + (quad ^ ((row>>1)&3))*16
// Reads (row=l15, per-lane quad) form a 64x16B bijection over the 1KiB tile
// -> conflict-free ds_read_b128. Writes spread 8 lanes/bank-slot (optimal).
__device__ __forceinline__ int qk_off(int tile, int row, int quad) {
    return tile * 512 + row * 32 + ((quad ^ ((row >> 1) & 3)) << 3);
}

// ---------------- kernel 1: CPB MLP (block per table point) ----------------
__global__ void cpb_kernel(const float* __restrict__ table,
                           const float* __restrict__ w1,
                           const float* __restrict__ b1,
                           const float* __restrict__ w2,
                           float* __restrict__ bv) {
    __shared__ float hid[512];
    int p = blockIdx.x;                 // 0..960
    float t0 = table[2 * p], t1 = table[2 * p + 1];
    int t = threadIdx.x;                // 256 threads
    for (int j = t; j < 512; j += 256) {
        float hv = fmaf(t0, w1[2 * j], fmaf(t1, w1[2 * j + 1], b1[j]));
        hid[j] = fmaxf(hv, 0.f);
    }
    __syncthreads();
    if (t < 192) {
        int h = t >> 5, l = t & 31;
        const float* w2h = w2 + h * 512;
        float acc = 0.f;
        for (int j = l; j < 512; j += 32) acc = fmaf(hid[j], w2h[j], acc);
        acc += __shfl_xor(acc, 1, 32);
        acc += __shfl_xor(acc, 2, 32);
        acc += __shfl_xor(acc, 4, 32);
        acc += __shfl_xor(acc, 8, 32);
        acc += __shfl_xor(acc, 16, 32);
        // fold -SHIFT2 into the bias grid
        if (l == 0) bv[h * 961 + p] = (16.f / (1.f + __expf(-acc))) * LOG2E - SHIFT2;
    }
}

// ---------------- kernel 2: MFMA attention ----------------
// block = one (window, head), 512 threads = 8 waves; wave w owns q-rows [w*32, w*32+32)
// Swapped QK^T (S^T = mfma(K,Q)): each lane's q-row is lane-local,
// P transposed to the PV A-fragment IN REGISTERS via v_cvt_pk_bf16_f32 +
// v_permlane32_swap_b32 (no LDS P buffer). Key-slot permutation (brev4 of
// key-pair index per 32-chunk) folded into V staging.
//
// Occupancy: launch_bounds(512, 6) pins 6 waves/SIMD (VGPR <= 85) so THREE
// blocks/CU are resident (VGPR was the binding limit at (512,4): flash-loop
// live set ~90+ regs -> only 2 blocks). S-tiles computed per-tl to cut peak
// S regs 16 -> 8 so the cap does not spill.
__global__ __launch_bounds__(512, 6) void attn_kernel(
    const float* __restrict__ qkv,
    const float* __restrict__ logit_scale,
    const float* __restrict__ bv,
    float* __restrict__ out)
{
    __shared__ __align__(16) short Qb[NTOK * HD];   // 16 KB  Q bf16, scale*log2e folded (tile-linear swizzled)
    __shared__ __align__(16) short Kb[NTOK * HD];   // 16 KB  K bf16 normalized (tile-linear swizzled)
    __shared__ __align__(16) short Vt[HD * 264];    // 16.9 KB V^T, stride 264, slot-permuted within 32-chunks
    __shared__ float Bv[961];                       // bias grid * log2e - SHIFT2

    const int t = threadIdx.x;
    const int h = blockIdx.x % NH;
    const int win = blockIdx.x / NH;
    const int b = win >> 4, wl = win & 15, wh = wl >> 2, ww = wl & 3;

    const float scale2 = __expf(fminf(logit_scale[h], 4.6051702f)) * LOG2E;

    for (int p = t; p < 961; p += 512) Bv[p] = bv[h * 961 + p];

    // ---- staging: threads 0..255 do Q,K; 256..511 do V^T
    {
        int n = (t < 256) ? t : (t - 256);
        if (t < 256) {
            int i = n >> 4, j = n & 15;
            int r = (wh * 16 + i + 8) & 63, c = (ww * 16 + j + 8) & 63;
            const float* base = qkv + ((long)(b * 4096 + r * 64 + c)) * CIN + h * HD;
            float qv[32], kv[32];
            const float4* qp = (const float4*)base;
            const float4* kp = (const float4*)(base + DIMO);
#pragma unroll
            for (int w = 0; w < 8; ++w) {
                float4 x = qp[w];
                qv[4 * w + 0] = x.x; qv[4 * w + 1] = x.y; qv[4 * w + 2] = x.z; qv[4 * w + 3] = x.w;
            }
#pragma unroll
            for (int w = 0; w < 8; ++w) {
                float4 x = kp[w];
                kv[4 * w + 0] = x.x; kv[4 * w + 1] = x.y; kv[4 * w + 2] = x.z; kv[4 * w + 3] = x.w;
            }
            float sq = 0.f, sk = 0.f;
#pragma unroll
            for (int d = 0; d < 32; ++d) { sq = fmaf(qv[d], qv[d], sq); sk = fmaf(kv[d], kv[d], sk); }
            float qs = scale2 / fmaxf(sqrtf(sq), 1e-12f);
            float ks = 1.f / fmaxf(sqrtf(sk), 1e-12f);
#pragma unroll
            for (int w = 0; w < 4; ++w) {
                int4v qd, kd;
#pragma unroll
                for (int e = 0; e < 4; ++e) {
                    qd[e] = pkbf(qv[8 * w + 2 * e] * qs, qv[8 * w + 2 * e + 1] * qs);
                    kd[e] = pkbf(kv[8 * w + 2 * e] * ks, kv[8 * w + 2 * e + 1] * ks);
                }
                union { int4v iv; short8 sv; } cq, ck;
                cq.iv = qd; ck.iv = kd;
                int off = qk_off(i, j, w);
                *(short8*)&Qb[off] = cq.sv;
                *(short8*)&Kb[off] = ck.sv;
            }
        } else {
            // V: thread handles tokens (2m, 2m+1) x d-half dh; writes packed b32
            int m = n & 127, dh = n >> 7;
            int i2 = m >> 3;                     // (2m)>>4
            int ja = (2 * m) & 15;               // even
            int r2 = (wh * 16 + i2 + 8) & 63;
            int ca = (ww * 16 + ja + 8) & 63;
            int cb = (ww * 16 + ja + 1 + 8) & 63;
            const float* ba = qkv + ((long)(b * 4096 + r2 * 64 + ca)) * CIN + h * HD + 2 * DIMO + dh * 16;
            const float* bb = qkv + ((long)(b * 4096 + r2 * 64 + cb)) * CIN + h * HD + 2 * DIMO + dh * 16;
            float va[16], vb[16];
            const float4* pa4 = (const float4*)ba;
            const float4* pb4 = (const float4*)bb;
#pragma unroll
            for (int w = 0; w < 4; ++w) {
                float4 A = pa4[w], B = pb4[w];
                va[4 * w + 0] = A.x; va[4 * w + 1] = A.y; va[4 * w + 2] = A.z; va[4 * w + 3] = A.w;
                vb[4 * w + 0] = B.x; vb[4 * w + 1] = B.y; vb[4 * w + 2] = B.z; vb[4 * w + 3] = B.w;
            }
            // slot-pair = brev4(token-pair index within 32-chunk)
            int u = m & 15;
            int jp = ((u & 1) << 3) | ((u & 2) << 1) | ((u & 4) >> 1) | ((u & 8) >> 3);
            int colb = (m >> 4) * 32 + 2 * jp;
#pragma unroll
            for (int di = 0; di < 16; ++di) {
                int pw = pkbf(va[di], vb[di]);   // lo = token 2m, hi = token 2m+1
                *(int*)&Vt[(dh * 16 + di) * 264 + colb] = pw;
            }
        }
    }
    __syncthreads();

    // ---- per-wave MFMA flash loop
    const int wv = t >> 6, lane = t & 63, quad = lane >> 4, l15 = lane & 15;

    const int trg[2] = {wv * 2, wv * 2 + 1};
    short8 bQ[2];
#pragma unroll
    for (int tl = 0; tl < 2; ++tl)
        bQ[tl] = *(const short8*)&Qb[qk_off(trg[tl], l15, quad)];

    const int gqr[2] = {grp6(wh * 16 + trg[0]), grp6(wh * 16 + trg[1])};
    const int gcl = grp6(ww * 16 + l15);        // q column-group: per-lane const
    float cm[4];
#pragma unroll
    for (int reg = 0; reg < 4; ++reg)
        cm[reg] = (gcl == grp6(ww * 16 + quad * 4 + reg)) ? 0.f : MNEG;

    f32x4 O[2][2];
    float lp[2] = {0.f, 0.f};
#pragma unroll
    for (int tl = 0; tl < 2; ++tl)
#pragma unroll
        for (int dtk = 0; dtk < 2; ++dtk) O[tl][dtk] = (f32x4){0.f, 0.f, 0.f, 0.f};

    const f32x4 Zero = (f32x4){0.f, 0.f, 0.f, 0.f};

    for (int c = 0; c < 8; ++c) {
        int ctg[2] = {2 * c, 2 * c + 1};
        short8 aK[2], bV[2];
#pragma unroll
        for (int ct = 0; ct < 2; ++ct)
            aK[ct] = *(const short8*)&Kb[qk_off(ctg[ct], l15, quad)];
#pragma unroll
        for (int dtk = 0; dtk < 2; ++dtk)
            bV[dtk] = *(const short8*)&Vt[(dtk * 16 + l15) * 264 + c * 32 + quad * 8];

        int gkr[2] = {grp6(wh * 16 + ctg[0]), grp6(wh * 16 + ctg[1])};

#pragma unroll
        for (int tl = 0; tl < 2; ++tl) {
            // S^T = K * Q^T : lane holds S^T[key=ctg*16+quad*4+reg][q=trg*16+l15]
            // per-tl S (peak 8 regs instead of 16)
            f32x4 S0 = __builtin_amdgcn_mfma_f32_16x16x32_bf16(aK[0], bQ[tl], Zero, 0, 0, 0);
            f32x4 S1 = __builtin_amdgcn_mfma_f32_16x16x32_bf16(aK[1], bQ[tl], Zero, 0, 0, 0);

            float ev[2][4];
#pragma unroll
            for (int ct = 0; ct < 2; ++ct) {
                const f32x4& Sc = ct ? S1 : S0;
                int rb = (trg[tl] - ctg[ct] + 15) * 31 + 15 + l15 - 4 * quad;
                bool rmatch = (gqr[tl] == gkr[ct]);       // wave-uniform
#pragma unroll
                for (int reg = 0; reg < 4; ++reg) {
                    float madd = rmatch ? cm[reg] : MNEG;
                    float arg = Sc[reg] + (Bv[rb - reg] + madd);
                    float e = __builtin_amdgcn_exp2f(arg);
                    ev[ct][reg] = e;
                    lp[tl] += e;                          // row q = trg*16+l15
                }
            }
            // pack to bf16 pairs; key-pairs: P0=(ct0 r4q,r4q+1) P1=(ct1 ...) P2=(ct0 r4q+2,+3) P3=(ct1 ...)
            int p0 = pkbf(ev[0][0], ev[0][1]);
            int p1 = pkbf(ev[1][0], ev[1][1]);
            int p2 = pkbf(ev[0][2], ev[0][3]);
            int p3 = pkbf(ev[1][2], ev[1][3]);
            // exchange halves across lane<32 / lane>=32
            asm("v_permlane32_swap_b32 %0, %1" : "+v"(p0), "+v"(p2));
            asm("v_permlane32_swap_b32 %0, %1" : "+v"(p1), "+v"(p3));
            // A-fragment dwords [p0,p1,p2,p3]; key-slot->token map = brev4 of pair
            // index (same permutation baked into Vt staging above)
            int4v wd = {p0, p1, p2, p3};
            union { int4v iv; short8 sv; } cvt; cvt.iv = wd;
            short8 aP = cvt.sv;
            O[tl][0] = __builtin_amdgcn_mfma_f32_16x16x32_bf16(aP, bV[0], O[tl][0], 0, 0, 0);
            O[tl][1] = __builtin_amdgcn_mfma_f32_16x16x32_bf16(aP, bV[1], O[tl][1], 0, 0, 0);
        }
    }

    // ---- softmax denominator: reduce across quads, then gather per output row
    const long pixb = (long)b * 4096;
#pragma unroll
    for (int tl = 0; tl < 2; ++tl) {
        float s = lp[tl];
        s += __shfl_xor(s, 16);
        s += __shfl_xor(s, 32);
        float invf = 1.f / s;                     // for q = trg*16 + l15
        int r = (wh * 16 + trg[tl] + 8) & 63;
#pragma unroll
        for (int reg = 0; reg < 4; ++reg) {
            float iv = __shfl(invf, quad * 4 + reg);   // row-sum for q = trg*16 + quad*4+reg
            int cpix = (ww * 16 + quad * 4 + reg + 8) & 63;
            float* op = out + (pixb + r * 64 + cpix) * DIMO + h * HD + l15;
            op[0]  = O[tl][0][reg] * iv;
            op[16] = O[tl][1][reg] * iv;
        }
    }
}

extern "C" void kernel_launch(void* const* d_in, const int* in_sizes, int n_in,
                              void* d_out, int out_size, void* d_ws, size_t ws_size,
                              hipStream_t stream) {
    const float* qkv         = (const float*)d_in[0];
    const float* table       = (const float*)d_in[1];
    // d_in[2] = mask   : recomputed from window-region groups
    const float* logit_scale = (const float*)d_in[3];
    const float* w1          = (const float*)d_in[4];
    const float* b1          = (const float*)d_in[5];
    const float* w2          = (const float*)d_in[6];
    // d_in[7] = index  : recomputed from relative coords
    float* out = (float*)d_out;
    float* bv  = (float*)d_ws;   // 6*961 floats

    cpb_kernel<<<961, 256, 0, stream>>>(table, w1, b1, w2, bv);
    attn_kernel<<<256 * NH, 512, 0, stream>>>(qkv, logit_scale, bv, out);
}